// Round 15
// baseline (170.926 us; speedup 1.0000x reference)
//
#include <hip/hip_runtime.h>
#include <math.h>

#define NEG_BIAS_F (-1.0e9f)

typedef float    f32x4 __attribute__((ext_vector_type(4)));
typedef _Float16 f16x8 __attribute__((ext_vector_type(8)));
typedef short    s16x8 __attribute__((ext_vector_type(8)));
using u16 = unsigned short;

constexpr int Bc = 8, Lc = 2048, Lq = 512, D = 512;
constexpr int NCH = 16;   // G2 row-chunks (= gridDim.y of G2), 128 rows each

__device__ __forceinline__ u16  f2h(float x) { _Float16 h = (_Float16)x; return __builtin_bit_cast(u16, h); }
__device__ __forceinline__ float h2f(u16 b)  { return (float)__builtin_bit_cast(_Float16, b); }

// async global->LDS, 16B per lane; LDS dest is wave-uniform base (+lane*16 by HW)
__device__ __forceinline__ void gload16(const u16* g, u16* lds) {
    __builtin_amdgcn_global_load_lds(
        (const __attribute__((address_space(1))) void*)g,
        (__attribute__((address_space(3))) void*)lds, 16, 0, 0);
}

__device__ __forceinline__ f32x4 mfma16h(s16x8 a, s16x8 b, f32x4 c) {
    return __builtin_amdgcn_mfma_f32_16x16x32_f16(
        __builtin_bit_cast(f16x8, a), __builtin_bit_cast(f16x8, b), c, 0, 0, 0);
}

// ---------------------------------------------------------------------------
// MFMA NT GEMM: C[m,n] = sum_k A[m,k]*B[n,k], f16. SPLITB: B as hi+lo pair
// (2-MFMA compensated). 128x128 tile, BK=32, 4 waves.
// RING-deep LDS pipeline with COUNTED vmcnt (T4): per iter
//   {vmcnt(min(rem,RING-2)*NLD), s_barrier, compute(t%RING), stage(t+RING-1)}.
// Safety: buf t's loads are always the OLDEST outstanding; the vmcnt proves
// them complete while later tiles stay in flight; each wave's vmcnt precedes
// its barrier => all waves' buf-t writes landed; stage(t+RING-1) overwrites a
// buffer last read in compute(t-1), complete before barrier t for every wave.
// EPI: 0 fp32->C1; 1 S-epilogue (+rowBias+colBias+mask) fp32->C1 AND fused
//        row/col softmax partial stats; 2 f16->Cb; 3 f16 hi/lo split;
//      4 out[0:D]=ctx,[D:2D]=v,[2D:3D]=ctx*v; 5 C1 = ctx*v.
// ---------------------------------------------------------------------------
template<bool SPLITB, int EPI, int SK, int RING>
__global__ __launch_bounds__(256)
void gemm_mfma(const u16* __restrict__ Ah, const u16* __restrict__ Bh,
               const u16* __restrict__ Bl,
               float* __restrict__ C1, u16* __restrict__ Cb, u16* __restrict__ Cb2,
               int M, int N, int K, int ld,
               long sA, long sB, long sC, long sCk, int ldc,
               const float* __restrict__ aux1, const float* __restrict__ aux2,
               const int* __restrict__ maskp, long sAux,
               float* __restrict__ rowM_out, float* __restrict__ rowS_out,
               float* __restrict__ colM_out, float* __restrict__ colS_out)
{
    constexpr int NB = SPLITB ? 3 : 2;
    __shared__ __align__(16) u16 sm[RING * NB * 4096];

    const int bz = blockIdx.z / SK, sk = blockIdx.z % SK;
    const u16* pA  = Ah + (long)bz * sA + (long)sk * K;
    const u16* pBh = Bh + (long)bz * sB + (long)sk * K;
    const u16* pBl = SPLITB ? (Bl + (long)bz * sB + (long)sk * K) : nullptr;

    const int m0 = blockIdx.y * 128, n0 = blockIdx.x * 128;
    const int tid = threadIdx.x, wid = tid >> 6, lane = tid & 63;
    const int wrow = (wid >> 1) * 64, wcol = (wid & 1) * 64;

    const int srow = wid * 16 + (lane >> 2);
    const int skel = (lane & 3) * 8;
    const int sldo = wid * 512;

    f32x4 acc[4][4] = {};

    auto stage = [&](int bsel, int k0) {
        u16* base = sm + bsel * (NB * 4096);
        #pragma unroll
        for (int r = 0; r < 2; ++r) {
            const long goA = (long)(m0 + srow + r * 64) * ld + k0 + skel;
            const long goB = (long)(n0 + srow + r * 64) * ld + k0 + skel;
            const int lo = sldo + r * 2048;
            gload16(pA + goA, base + lo);
            gload16(pBh + goB, base + 4096 + lo);
            if (SPLITB) gload16(pBl + goB, base + 8192 + lo);
        }
    };
    auto compute = [&](int bsel) {
        const u16* As  = sm + bsel * (NB * 4096);
        const u16* BsH = As + 4096;
        const u16* BsL = As + 8192;
        s16x8 a[4], b[4], bl[4];
        #pragma unroll
        for (int f = 0; f < 4; ++f) {
            const int ra = (wrow + f * 16 + (lane & 15)) * 32 + (lane >> 4) * 8;
            const int rb = (wcol + f * 16 + (lane & 15)) * 32 + (lane >> 4) * 8;
            a[f] = *(const s16x8*)&As[ra];
            b[f] = *(const s16x8*)&BsH[rb];
            if (SPLITB) bl[f] = *(const s16x8*)&BsL[rb];
        }
        #pragma unroll
        for (int i = 0; i < 4; ++i)
            #pragma unroll
            for (int j = 0; j < 4; ++j) {
                acc[i][j] = mfma16h(a[i], b[j], acc[i][j]);
                if (SPLITB) acc[i][j] = mfma16h(a[i], bl[j], acc[i][j]);
            }
    };

    const int NT = K / 32;                 // >= RING for all call sites
    #pragma unroll
    for (int p = 0; p < RING - 1; ++p) stage(p, p * 32);
    for (int t = 0; t < NT; ++t) {
        const int rem = NT - 1 - t;        // tiles still to compute after t
        // leave min(rem, RING-2) tiles' loads in flight; buf t is the oldest
        if constexpr (RING == 4) {
            if (rem >= 2)      asm volatile("s_waitcnt vmcnt(8)" ::: "memory");
            else if (rem == 1) asm volatile("s_waitcnt vmcnt(4)" ::: "memory");
            else               asm volatile("s_waitcnt vmcnt(0)" ::: "memory");
        } else {               // RING == 3
            if (rem >= 1) {
                if constexpr (SPLITB) asm volatile("s_waitcnt vmcnt(6)" ::: "memory");
                else                  asm volatile("s_waitcnt vmcnt(4)" ::: "memory");
            } else {
                asm volatile("s_waitcnt vmcnt(0)" ::: "memory");
            }
        }
        __builtin_amdgcn_s_barrier();
        compute(t % RING);
        if (t + RING - 1 < NT) stage((t + RING - 1) % RING, (t + RING - 1) * 32);
    }
    __syncthreads();                       // quiesce before LDS reuse in epilogue

    // C/D layout (m89-verified): col = lane&15, row = (lane>>4)*4 + reg
    const long cBase = (long)bz * sC + (long)sk * sCk;

    if constexpr (EPI == 1) {
        // ---- fused store + row/col softmax partial stats ----
        float* redRM = (float*)sm;          // [2][128] row halves (by wid&1)
        float* redRS = redRM + 256;
        float* redCM = redRS + 256;         // [2][128] col halves (by wid>>1)
        float* redCS = redCM + 256;

        float cb[4];
        #pragma unroll
        for (int j = 0; j < 4; ++j)
            cb[j] = aux2[(long)bz * N + n0 + wcol + j * 16 + (lane & 15)];
        float cm[4], cs[4];
        #pragma unroll
        for (int j = 0; j < 4; ++j) { cm[j] = -INFINITY; cs[j] = 0.f; }

        #pragma unroll
        for (int i = 0; i < 4; ++i) {
            #pragma unroll
            for (int r = 0; r < 4; ++r) {
                const int rowLocal = wrow + i * 16 + (lane >> 4) * 4 + r;
                const int row = m0 + rowLocal;
                const float rb = aux1[(long)bz * M + row];
                const int* mrow = maskp + (long)bz * sAux + (long)row * N + n0 + wcol + (lane & 15);
                float v4[4];
                #pragma unroll
                for (int j = 0; j < 4; ++j) {
                    float v = acc[i][j][r] + rb + cb[j];
                    v += mrow[j * 16] ? 0.f : NEG_BIAS_F;
                    v4[j] = v;
                    C1[cBase + (long)row * ldc + n0 + wcol + j * 16 + (lane & 15)] = v;
                    float nm = fmaxf(cm[j], v);
                    cs[j] = cs[j] * __expf(cm[j] - nm) + __expf(v - nm);
                    cm[j] = nm;
                }
                float rm = fmaxf(fmaxf(v4[0], v4[1]), fmaxf(v4[2], v4[3]));
                float rs = __expf(v4[0] - rm) + __expf(v4[1] - rm)
                         + __expf(v4[2] - rm) + __expf(v4[3] - rm);
                #pragma unroll
                for (int off = 1; off <= 8; off <<= 1) {
                    float om = __shfl_xor(rm, off);
                    float os = __shfl_xor(rs, off);
                    float nm = fmaxf(rm, om);
                    rs = rs * __expf(rm - nm) + os * __expf(om - nm);
                    rm = nm;
                }
                if ((lane & 15) == 0) {
                    redRM[(wid & 1) * 128 + rowLocal] = rm;
                    redRS[(wid & 1) * 128 + rowLocal] = rs;
                }
            }
        }
        #pragma unroll
        for (int j = 0; j < 4; ++j) {
            #pragma unroll
            for (int off = 16; off <= 32; off <<= 1) {
                float om = __shfl_xor(cm[j], off);
                float os = __shfl_xor(cs[j], off);
                float nm = fmaxf(cm[j], om);
                cs[j] = cs[j] * __expf(cm[j] - nm) + os * __expf(om - nm);
                cm[j] = nm;
            }
            if ((lane >> 4) == 0) {
                const int colLocal = wcol + j * 16 + (lane & 15);
                redCM[(wid >> 1) * 128 + colLocal] = cm[j];
                redCS[(wid >> 1) * 128 + colLocal] = cs[j];
            }
        }
        __syncthreads();
        if (tid < 128) {
            float ma = redRM[tid], mb = redRM[128 + tid];
            float sa = redRS[tid], sb = redRS[128 + tid];
            float mm = fmaxf(ma, mb);
            float ss = sa * __expf(ma - mm) + sb * __expf(mb - mm);
            rowM_out[((long)bz * M + m0 + tid) * 4 + blockIdx.x] = mm;
            rowS_out[((long)bz * M + m0 + tid) * 4 + blockIdx.x] = ss;
        } else {
            const int ct = tid - 128;
            float ma = redCM[ct], mb = redCM[128 + ct];
            float sa = redCS[ct], sb = redCS[128 + ct];
            float mm = fmaxf(ma, mb);
            float ss = sa * __expf(ma - mm) + sb * __expf(mb - mm);
            colM_out[((long)bz * NCH + blockIdx.y) * N + n0 + ct] = mm;
            colS_out[((long)bz * NCH + blockIdx.y) * N + n0 + ct] = ss;
        }
    } else {
        #pragma unroll
        for (int i = 0; i < 4; ++i) {
            #pragma unroll
            for (int r = 0; r < 4; ++r) {
                const int row = m0 + wrow + i * 16 + (lane >> 4) * 4 + r;
                #pragma unroll
                for (int j = 0; j < 4; ++j) {
                    const int col = n0 + wcol + j * 16 + (lane & 15);
                    float v = acc[i][j][r];
                    if constexpr (EPI == 0) {
                        C1[cBase + (long)row * ldc + col] = v;
                    } else if constexpr (EPI == 2) {
                        Cb[cBase + (long)row * ldc + col] = f2h(v);
                    } else if constexpr (EPI == 3) {
                        u16 h = f2h(v);
                        Cb[cBase + (long)row * ldc + col] = h;
                        Cb2[cBase + (long)row * ldc + col] = f2h(v - h2f(h));
                    } else if constexpr (EPI == 4) {
                        float c = aux1[(long)bz * sAux + (long)row * D + col];
                        float* p = C1 + cBase + (long)row * ldc;
                        p[col] = c;
                        p[D + col] = v;
                        p[2 * D + col] = c * v;
                    } else {  // 5
                        float c = aux1[(long)bz * sAux + (long)row * D + col];
                        C1[cBase + (long)row * ldc + col] = c * v;
                    }
                }
            }
        }
    }
}

// ---------------------------------------------------------------------------
// Fused fp32->f16 convert + row dot with [D,1] weight. One wave per row.
// ---------------------------------------------------------------------------
__global__ __launch_bounds__(256)
void cvtdot(const float* __restrict__ X, const float* __restrict__ wv,
            u16* __restrict__ x16, float* __restrict__ dotv, long rows)
{
    long r = (long)blockIdx.x * 4 + (threadIdx.x >> 6);
    int lane = threadIdx.x & 63;
    if (r >= rows) return;
    const float4* xr = (const float4*)(X + r * D);
    const float4* wr = (const float4*)wv;
    float4 a0 = xr[lane * 2], a1 = xr[lane * 2 + 1];
    float4 b0 = wr[lane * 2], b1 = wr[lane * 2 + 1];
    float s = a0.x * b0.x + a0.y * b0.y + a0.z * b0.z + a0.w * b0.w
            + a1.x * b1.x + a1.y * b1.y + a1.z * b1.z + a1.w * b1.w;
    #pragma unroll
    for (int off = 32; off; off >>= 1) s += __shfl_xor(s, off);
    if (lane == 0) dotv[r] = s;
    ushort4 h0, h1;
    h0.x = f2h(a0.x); h0.y = f2h(a0.y); h0.z = f2h(a0.z); h0.w = f2h(a0.w);
    h1.x = f2h(a1.x); h1.y = f2h(a1.y); h1.z = f2h(a1.z); h1.w = f2h(a1.w);
    *(ushort4*)&x16[r * D + lane * 8] = h0;
    *(ushort4*)&x16[r * D + lane * 8 + 4] = h1;
}

// ---------------------------------------------------------------------------
// fp32 -> (hi, lo) f16 split (dot_weights only)
// ---------------------------------------------------------------------------
__global__ __launch_bounds__(256)
void split_f16(const float* __restrict__ x, u16* __restrict__ hi, u16* __restrict__ lo, long n4)
{
    long i = (long)blockIdx.x * 256 + threadIdx.x;
    if (i >= n4) return;
    float4 v = ((const float4*)x)[i];
    ushort4 h, l;
    h.x = f2h(v.x); l.x = f2h(v.x - h2f(h.x));
    h.y = f2h(v.y); l.y = f2h(v.y - h2f(h.y));
    h.z = f2h(v.z); l.z = f2h(v.z - h2f(h.z));
    h.w = f2h(v.w); l.w = f2h(v.w - h2f(h.w));
    ((ushort4*)hi)[i] = h;
    ((ushort4*)lo)[i] = l;
}

// ---------------------------------------------------------------------------
// G1 split-K reduce: Kt = f16(p0+p1) single (fp32 partials)
// ---------------------------------------------------------------------------
__global__ __launch_bounds__(256)
void g1reduce(const float* __restrict__ p, u16* __restrict__ o, long n4)
{
    long i = (long)blockIdx.x * 256 + threadIdx.x;
    if (i >= n4) return;
    float4 a = ((const float4*)p)[i];
    float4 b = ((const float4*)(p + (long)4096 * 512))[i];
    ushort4 h;
    h.x = f2h(a.x + b.x);
    h.y = f2h(a.y + b.y);
    h.z = f2h(a.z + b.z);
    h.w = f2h(a.w + b.w);
    ((ushort4*)o)[i] = h;
}

// ---------------------------------------------------------------------------
// G4 split-K reduce: Tt = f16(p0+p1), f16 partials
// ---------------------------------------------------------------------------
__global__ __launch_bounds__(256)
void g4reduce(const u16* __restrict__ p, u16* __restrict__ o, long n4)
{
    long i = (long)blockIdx.x * 256 + threadIdx.x;
    if (i >= n4) return;
    ushort4 a = ((const ushort4*)p)[i];
    ushort4 b = ((const ushort4*)(p + (long)Bc * D * Lq))[i];
    ushort4 r;
    r.x = f2h(h2f(a.x) + h2f(b.x));
    r.y = f2h(h2f(a.y) + h2f(b.y));
    r.z = f2h(h2f(a.z) + h2f(b.z));
    r.w = f2h(h2f(a.w) + h2f(b.w));
    ((ushort4*)o)[i] = r;
}

// ---------------------------------------------------------------------------
// Merge partial stats: rows (4 chunks) -> FmR/FrR[B*Lc]; cols (16 chunks)
// -> FmC/FrC[B*Lq]. One thread per output cell.
// ---------------------------------------------------------------------------
__global__ __launch_bounds__(256)
void stat_merge(const float* __restrict__ Rmax, const float* __restrict__ Rsum,
                const float* __restrict__ Pmax, const float* __restrict__ Psum,
                float* __restrict__ FmR, float* __restrict__ FrR,
                float* __restrict__ FmC, float* __restrict__ FrC)
{
    int i = blockIdx.x * 256 + threadIdx.x;
    if (i < Bc * Lc) {
        float4 m4 = ((const float4*)Rmax)[i];
        float4 s4 = ((const float4*)Rsum)[i];
        float m = fmaxf(fmaxf(m4.x, m4.y), fmaxf(m4.z, m4.w));
        float s = s4.x * __expf(m4.x - m) + s4.y * __expf(m4.y - m)
                + s4.z * __expf(m4.z - m) + s4.w * __expf(m4.w - m);
        FmR[i] = m;
        FrR[i] = 1.0f / s;
    } else if (i < Bc * Lc + Bc * Lq) {
        int k = i - Bc * Lc;
        int b = k >> 9, q = k & (Lq - 1);
        const float* pm = Pmax + (long)b * NCH * Lq + q;
        const float* ps = Psum + (long)b * NCH * Lq + q;
        float m = -INFINITY;
        #pragma unroll
        for (int ch = 0; ch < NCH; ++ch) m = fmaxf(m, pm[ch * Lq]);
        float s = 0.f;
        #pragma unroll
        for (int ch = 0; ch < NCH; ++ch) s += ps[ch * Lq] * __expf(pm[ch * Lq] - m);
        FmC[k] = m;
        FrC[k] = 1.0f / s;
    }
}

// ---------------------------------------------------------------------------
// One S read -> BOTH softmax outputs: c2q[row][col] (row-normalized, f16)
// and q2cT[col][row] (col-normalized, transposed via LDS, f16).
// ---------------------------------------------------------------------------
__global__ __launch_bounds__(256)
void softmax_apply(const float* __restrict__ S, u16* __restrict__ c2q,
                   u16* __restrict__ q2cT,
                   const float* __restrict__ FmR, const float* __restrict__ FrR,
                   const float* __restrict__ FmC, const float* __restrict__ FrC)
{
    __shared__ float t[32][33];
    const int b = blockIdx.z;
    const int r0 = blockIdx.y * 32, c0 = blockIdx.x * 32;
    const int tid = threadIdx.x;
    const int rr = tid >> 3, cc = (tid & 7) * 4;
    float4 v = *(const float4*)&S[((long)b * Lc + r0 + rr) * Lq + c0 + cc];
    t[rr][cc] = v.x; t[rr][cc + 1] = v.y; t[rr][cc + 2] = v.z; t[rr][cc + 3] = v.w;
    const float fm = FmR[(long)b * Lc + r0 + rr], fr = FrR[(long)b * Lc + r0 + rr];
    ushort4 o;
    o.x = f2h(__expf(v.x - fm) * fr);
    o.y = f2h(__expf(v.y - fm) * fr);
    o.z = f2h(__expf(v.z - fm) * fr);
    o.w = f2h(__expf(v.w - fm) * fr);
    *(ushort4*)&c2q[((long)b * Lc + r0 + rr) * Lq + c0 + cc] = o;
    __syncthreads();
    const int oc = tid >> 3, orr = (tid & 7) * 4;
    const float fmc = FmC[(long)b * Lq + c0 + oc], frc = FrC[(long)b * Lq + c0 + oc];
    ushort4 q;
    q.x = f2h(__expf(t[orr + 0][oc] - fmc) * frc);
    q.y = f2h(__expf(t[orr + 1][oc] - fmc) * frc);
    q.z = f2h(__expf(t[orr + 2][oc] - fmc) * frc);
    q.w = f2h(__expf(t[orr + 3][oc] - fmc) * frc);
    *(ushort4*)&q2cT[((long)b * Lq + c0 + oc) * Lc + r0 + orr] = q;
}

// ---------------------------------------------------------------------------
// LDS-tiled transpose: fp32 [R,C] -> f16 [C,R]
// ---------------------------------------------------------------------------
__global__ __launch_bounds__(256)
void transpose_cvt(const float* __restrict__ in, u16* __restrict__ out,
                   int R, int C, long sIn, long sOut)
{
    __shared__ float t[32][33];
    const int b = blockIdx.z;
    in += (long)b * sIn; out += (long)b * sOut;
    const int r0 = blockIdx.y * 32, c0 = blockIdx.x * 32;
    const int tid = threadIdx.x;
    {
        const int rr = tid >> 3, cc = (tid & 7) * 4;
        float4 v = *(const float4*)&in[(long)(r0 + rr) * C + c0 + cc];
        t[rr][cc] = v.x; t[rr][cc + 1] = v.y; t[rr][cc + 2] = v.z; t[rr][cc + 3] = v.w;
    }
    __syncthreads();
    const int oc = tid >> 3, orr = (tid & 7) * 4;
    ushort4 o;
    o.x = f2h(t[orr + 0][oc]); o.y = f2h(t[orr + 1][oc]);
    o.z = f2h(t[orr + 2][oc]); o.w = f2h(t[orr + 3][oc]);
    *(ushort4*)&out[(long)(c0 + oc) * R + r0 + orr] = o;
}

// ---------------------------------------------------------------------------
// LDS-tiled transpose: f16 [R,C] -> f16 [C,R]
// ---------------------------------------------------------------------------
__global__ __launch_bounds__(256)
void transpose_u16(const u16* __restrict__ in, u16* __restrict__ out,
                   int R, int C, long sIn, long sOut)
{
    __shared__ u16 t[32][34];
    const int b = blockIdx.z;
    in += (long)b * sIn; out += (long)b * sOut;
    const int r0 = blockIdx.y * 32, c0 = blockIdx.x * 32;
    const int tid = threadIdx.x;
    {
        const int rr = tid >> 3, cc = (tid & 7) * 4;
        ushort4 v = *(const ushort4*)&in[(long)(r0 + rr) * C + c0 + cc];
        t[rr][cc] = v.x; t[rr][cc + 1] = v.y; t[rr][cc + 2] = v.z; t[rr][cc + 3] = v.w;
    }
    __syncthreads();
    const int oc = tid >> 3, orr = (tid & 7) * 4;
    ushort4 o;
    o.x = t[orr + 0][oc]; o.y = t[orr + 1][oc]; o.z = t[orr + 2][oc]; o.w = t[orr + 3][oc];
    *(ushort4*)&out[(long)(c0 + oc) * R + r0 + orr] = o;
}

extern "C" void kernel_launch(void* const* d_in, const int* in_sizes, int n_in,
                              void* d_out, int out_size, void* d_ws, size_t ws_size,
                              hipStream_t stream)
{
    const float* context = (const float*)d_in[0];
    const float* query   = (const float*)d_in[1];
    const int*   mask    = (const int*)d_in[2];
    const float* qWt     = (const float*)d_in[3];
    const float* cWt     = (const float*)d_in[4];
    const float* dotW    = (const float*)d_in[5];
    float* out = (float*)d_out;

    char* w = (char*)d_ws;
    size_t off = 0;
    auto alloc = [&](size_t bytes) { void* p = w + off; off += (bytes + 255) & ~(size_t)255; return p; };

    // Region 1: ctx f16 during pre-softmax; c2q after G2 (alias; ctx16's last reader is G2)
    u16* ctx16 = (u16*)alloc((size_t)Bc * Lc * D * 2);
    u16* c2q   = ctx16;
    // Region 2: q2cT (written after G2)
    u16* q2cT = (u16*)alloc((size_t)Bc * Lq * Lc * 2);
    // Region 3: S fp32. Hosts G1 fp32 partials BEFORE G2 writes S; hosts
    // ctxT/qT/Tt after the last S read (softmax_apply).
    float* S = (float*)alloc((size_t)Bc * Lc * Lq * 4);
    float* g1part = S;                                          // [2][4096][512] fp32
    u16* ctxT = (u16*)S;                                        // [B, D, Lc]
    u16* qT   = (u16*)((char*)S + (size_t)Bc * D * Lc * 2);     // [B, D, Lq]
    u16* Tt   = (u16*)((char*)S + (size_t)Bc * D * Lc * 2
                               + (size_t)Bc * D * Lq * 2);      // [B, D, Lq]
    // Fixed region
    u16* q16   = (u16*)alloc((size_t)Bc * Lq * D * 2);
    u16* w_hi  = (u16*)alloc((size_t)D * D * 2);
    u16* w_lo  = (u16*)alloc((size_t)D * D * 2);
    u16* Kt    = (u16*)alloc((size_t)Bc * Lq * D * 2);   // single f16 Kt
    u16* KtPad = (u16*)alloc((size_t)Bc * Lq * D * 2);   // keeps g4part region sized
    u16* g4part = Kt;   // [2][B][D][Lq] f16 spans Kt+KtPad (dead after G2)
    float* cw   = (float*)alloc((size_t)Bc * Lc * 4);
    float* qw   = (float*)alloc((size_t)Bc * Lq * 4);
    float* Rmax = (float*)alloc((size_t)Bc * Lc * 4 * 4);   // [B][Lc][4]
    float* Rsum = (float*)alloc((size_t)Bc * Lc * 4 * 4);
    float* Pmax = (float*)alloc((size_t)Bc * NCH * Lq * 4); // [B][16][Lq]
    float* Psum = (float*)alloc((size_t)Bc * NCH * Lq * 4);
    float* FmR  = (float*)alloc((size_t)Bc * Lc * 4);
    float* FrR  = (float*)alloc((size_t)Bc * Lc * 4);
    float* FmC  = (float*)alloc((size_t)Bc * Lq * 4);
    float* FrC  = (float*)alloc((size_t)Bc * Lq * 4);
    (void)KtPad;

    // 1) fused convert + row dots; weight hi/lo split
    cvtdot<<<dim3(Bc * Lc / 4), 256, 0, stream>>>(context, cWt, ctx16, cw, (long)Bc * Lc);
    cvtdot<<<dim3(Bc * Lq / 4), 256, 0, stream>>>(query, qWt, q16, qw, (long)Bc * Lq);
    split_f16<<<dim3(D * D / 4 / 256), 256, 0, stream>>>(dotW, w_hi, w_lo, (long)D * D / 4);

    // 2) G1 splitK=2: partials = q16 @ W^T halves (M=4096 flat, fp32; W hi/lo split)
    gemm_mfma<true, 0, 2, 3><<<dim3(4, 32, 2), 256, 0, stream>>>(
        q16, w_hi, w_lo, g1part, nullptr, nullptr,
        4096, D, 256, 512, 0, 0, 0, (long)4096 * 512, 512,
        nullptr, nullptr, nullptr, 0, nullptr, nullptr, nullptr, nullptr);
    g1reduce<<<dim3(2048), 256, 0, stream>>>(g1part, Kt, (long)4096 * 512 / 4);

    // 3) G2: S[b] = ctx_b @ Kt_b^T + biases + mask; fused row/col stat partials
    gemm_mfma<false, 1, 1, 4><<<dim3(4, 16, Bc), 256, 0, stream>>>(
        ctx16, Kt, nullptr, S, nullptr, nullptr,
        Lc, Lq, D, 512, (long)Lc * D, (long)Lq * D, (long)Lc * Lq, 0, Lq,
        cw, qw, mask, (long)Lc * Lq, Rmax, Rsum, Pmax, Psum);

    // 4) merge stats (rows 4->1, cols 16->1)
    stat_merge<<<dim3((Bc * Lc + Bc * Lq + 255) / 256), 256, 0, stream>>>(
        Rmax, Rsum, Pmax, Psum, FmR, FrR, FmC, FrC);

    // 5) one S read -> c2q (overwrites ctx16) + q2cT
    softmax_apply<<<dim3(Lq / 32, Lc / 32, Bc), 256, 0, stream>>>(
        S, c2q, q2cT, FmR, FrR, FmC, FrC);

    // 6) transposed f16 copies into the now-dead S region
    transpose_cvt<<<dim3(D / 32, Lc / 32, Bc), 256, 0, stream>>>(
        context, ctxT, Lc, D, (long)Lc * D, (long)D * Lc);
    transpose_u16<<<dim3(D / 32, Lq / 32, Bc), 256, 0, stream>>>(
        q16, qT, Lq, D, (long)Lq * D, (long)D * Lq);

    // 7) G4 splitK=2: Tt partials = ctxT @ q2cT^T halves (f16 partials in Kt region)
    gemm_mfma<false, 2, 2, 4><<<dim3(4, 4, Bc * 2), 256, 0, stream>>>(
        ctxT, q2cT, nullptr, nullptr, g4part, nullptr,
        D, Lq, 1024, 2048, (long)D * Lc, (long)Lq * Lc, (long)D * Lq, (long)Bc * D * Lq, Lq,
        nullptr, nullptr, nullptr, 0, nullptr, nullptr, nullptr, nullptr);
    g4reduce<<<dim3(2048), 256, 0, stream>>>(g4part, Tt, (long)Bc * D * Lq / 4);

    // 8) G3: ctq = c2q @ qT^T; epilogue writes out[0:D]=ctx, [D:2D]=ctq, [2D:3D]=ctx*ctq
    gemm_mfma<false, 4, 1, 4><<<dim3(4, 16, Bc), 256, 0, stream>>>(
        c2q, qT, nullptr, out, nullptr, nullptr,
        Lc, D, Lq, 512, (long)Lc * Lq, (long)D * Lq, (long)Lc * 4 * D, 0, 4 * D,
        context, nullptr, nullptr, (long)Lc * D, nullptr, nullptr, nullptr, nullptr);

    // 9) G5: qtc = c2q @ Tt^T; epilogue writes out[3D:4D] = ctx*qtc
    gemm_mfma<false, 5, 1, 4><<<dim3(4, 16, Bc), 256, 0, stream>>>(
        c2q, Tt, nullptr, out + 3 * D, nullptr, nullptr,
        Lc, D, Lq, 512, (long)Lc * Lq, (long)D * Lq, (long)Lc * 4 * D, 0, 4 * D,
        context, nullptr, nullptr, (long)Lc * D, nullptr, nullptr, nullptr, nullptr);
}

// Round 16
// 168.249 us; speedup vs baseline: 1.0159x; 1.0159x over previous
//
#include <hip/hip_runtime.h>
#include <math.h>

#define NEG_BIAS_F (-1.0e9f)

typedef float    f32x4 __attribute__((ext_vector_type(4)));
typedef _Float16 f16x8 __attribute__((ext_vector_type(8)));
typedef short    s16x8 __attribute__((ext_vector_type(8)));
using u16 = unsigned short;

constexpr int Bc = 8, Lc = 2048, Lq = 512, D = 512;
constexpr int NCH = 16;   // G2 row-chunks (= gridDim.y of G2), 128 rows each

__device__ __forceinline__ u16  f2h(float x) { _Float16 h = (_Float16)x; return __builtin_bit_cast(u16, h); }
__device__ __forceinline__ float h2f(u16 b)  { return (float)__builtin_bit_cast(_Float16, b); }

// async global->LDS, 16B per lane; LDS dest is wave-uniform base (+lane*16 by HW)
__device__ __forceinline__ void gload16(const u16* g, u16* lds) {
    __builtin_amdgcn_global_load_lds(
        (const __attribute__((address_space(1))) void*)g,
        (__attribute__((address_space(3))) void*)lds, 16, 0, 0);
}

__device__ __forceinline__ f32x4 mfma16h(s16x8 a, s16x8 b, f32x4 c) {
    return __builtin_amdgcn_mfma_f32_16x16x32_f16(
        __builtin_bit_cast(f16x8, a), __builtin_bit_cast(f16x8, b), c, 0, 0, 0);
}

// ---------------------------------------------------------------------------
// MFMA NT GEMM: C[m,n] = sum_k A[m,k]*B[n,k], f16. SPLITB: B as hi+lo pair
// (2-MFMA compensated). 128x128 tile, BK=32, 4 waves.
// RING-deep LDS pipeline with COUNTED vmcnt (T4): per iter
//   {vmcnt(min(rem,RING-2)*NLD), s_barrier, compute(t%RING), stage(t+RING-1)}.
// Safety: buf t's loads are always the OLDEST outstanding; the vmcnt proves
// them complete while later tiles stay in flight; each wave's vmcnt precedes
// its barrier => all waves' buf-t writes landed; stage(t+RING-1) overwrites a
// buffer last read in compute(t-1), complete before barrier t for every wave.
// EPI: 0 fp32->C1; 1 S-epilogue (+rowBias+colBias+mask) fp32->C1 AND fused
//        row/col softmax partial stats; 2 f16->Cb;
//      4 out[0:D]=f16ctx,[D:2D]=v,[2D:3D]=f16ctx*v (ctxh = f16 context);
//      5 C1 = f16ctx*v.
// ---------------------------------------------------------------------------
template<bool SPLITB, int EPI, int SK, int RING>
__global__ __launch_bounds__(256)
void gemm_mfma(const u16* __restrict__ Ah, const u16* __restrict__ Bh,
               const u16* __restrict__ Bl,
               float* __restrict__ C1, u16* __restrict__ Cb,
               int M, int N, int K, int ld,
               long sA, long sB, long sC, long sCk, int ldc,
               const float* __restrict__ aux1, const float* __restrict__ aux2,
               const int* __restrict__ maskp, long sAux,
               const u16* __restrict__ ctxh,
               float* __restrict__ rowM_out, float* __restrict__ rowS_out,
               float* __restrict__ colM_out, float* __restrict__ colS_out)
{
    constexpr int NB = SPLITB ? 3 : 2;
    __shared__ __align__(16) u16 sm[RING * NB * 4096];

    const int bz = blockIdx.z / SK, sk = blockIdx.z % SK;
    const u16* pA  = Ah + (long)bz * sA + (long)sk * K;
    const u16* pBh = Bh + (long)bz * sB + (long)sk * K;
    const u16* pBl = SPLITB ? (Bl + (long)bz * sB + (long)sk * K) : nullptr;

    const int m0 = blockIdx.y * 128, n0 = blockIdx.x * 128;
    const int tid = threadIdx.x, wid = tid >> 6, lane = tid & 63;
    const int wrow = (wid >> 1) * 64, wcol = (wid & 1) * 64;

    const int srow = wid * 16 + (lane >> 2);
    const int skel = (lane & 3) * 8;
    const int sldo = wid * 512;

    f32x4 acc[4][4] = {};

    auto stage = [&](int bsel, int k0) {
        u16* base = sm + bsel * (NB * 4096);
        #pragma unroll
        for (int r = 0; r < 2; ++r) {
            const long goA = (long)(m0 + srow + r * 64) * ld + k0 + skel;
            const long goB = (long)(n0 + srow + r * 64) * ld + k0 + skel;
            const int lo = sldo + r * 2048;
            gload16(pA + goA, base + lo);
            gload16(pBh + goB, base + 4096 + lo);
            if (SPLITB) gload16(pBl + goB, base + 8192 + lo);
        }
    };
    auto compute = [&](int bsel) {
        const u16* As  = sm + bsel * (NB * 4096);
        const u16* BsH = As + 4096;
        const u16* BsL = As + 8192;
        s16x8 a[4], b[4], bl[4];
        #pragma unroll
        for (int f = 0; f < 4; ++f) {
            const int ra = (wrow + f * 16 + (lane & 15)) * 32 + (lane >> 4) * 8;
            const int rb = (wcol + f * 16 + (lane & 15)) * 32 + (lane >> 4) * 8;
            a[f] = *(const s16x8*)&As[ra];
            b[f] = *(const s16x8*)&BsH[rb];
            if (SPLITB) bl[f] = *(const s16x8*)&BsL[rb];
        }
        #pragma unroll
        for (int i = 0; i < 4; ++i)
            #pragma unroll
            for (int j = 0; j < 4; ++j) {
                acc[i][j] = mfma16h(a[i], b[j], acc[i][j]);
                if (SPLITB) acc[i][j] = mfma16h(a[i], bl[j], acc[i][j]);
            }
    };

    const int NT = K / 32;                 // >= RING for all call sites
    #pragma unroll
    for (int p = 0; p < RING - 1; ++p) stage(p, p * 32);
    for (int t = 0; t < NT; ++t) {
        const int rem = NT - 1 - t;
        if constexpr (RING == 4) {
            if (rem >= 2)      asm volatile("s_waitcnt vmcnt(8)" ::: "memory");
            else if (rem == 1) asm volatile("s_waitcnt vmcnt(4)" ::: "memory");
            else               asm volatile("s_waitcnt vmcnt(0)" ::: "memory");
        } else {               // RING == 3
            if (rem >= 1) {
                if constexpr (SPLITB) asm volatile("s_waitcnt vmcnt(6)" ::: "memory");
                else                  asm volatile("s_waitcnt vmcnt(4)" ::: "memory");
            } else {
                asm volatile("s_waitcnt vmcnt(0)" ::: "memory");
            }
        }
        __builtin_amdgcn_s_barrier();
        compute(t % RING);
        if (t + RING - 1 < NT) stage((t + RING - 1) % RING, (t + RING - 1) * 32);
    }
    __syncthreads();                       // quiesce before LDS reuse in epilogue

    // C/D layout (m89-verified): col = lane&15, row = (lane>>4)*4 + reg
    const long cBase = (long)bz * sC + (long)sk * sCk;

    if constexpr (EPI == 1) {
        // ---- fused store + row/col softmax partial stats ----
        float* redRM = (float*)sm;          // [2][128] row halves (by wid&1)
        float* redRS = redRM + 256;
        float* redCM = redRS + 256;         // [2][128] col halves (by wid>>1)
        float* redCS = redCM + 256;

        float cb[4];
        #pragma unroll
        for (int j = 0; j < 4; ++j)
            cb[j] = aux2[(long)bz * N + n0 + wcol + j * 16 + (lane & 15)];
        float cm[4], cs[4];
        #pragma unroll
        for (int j = 0; j < 4; ++j) { cm[j] = -INFINITY; cs[j] = 0.f; }

        #pragma unroll
        for (int i = 0; i < 4; ++i) {
            #pragma unroll
            for (int r = 0; r < 4; ++r) {
                const int rowLocal = wrow + i * 16 + (lane >> 4) * 4 + r;
                const int row = m0 + rowLocal;
                const float rb = aux1[(long)bz * M + row];
                const int* mrow = maskp + (long)bz * sAux + (long)row * N + n0 + wcol + (lane & 15);
                float v4[4];
                #pragma unroll
                for (int j = 0; j < 4; ++j) {
                    float v = acc[i][j][r] + rb + cb[j];
                    v += mrow[j * 16] ? 0.f : NEG_BIAS_F;
                    v4[j] = v;
                    C1[cBase + (long)row * ldc + n0 + wcol + j * 16 + (lane & 15)] = v;
                    float nm = fmaxf(cm[j], v);
                    cs[j] = cs[j] * __expf(cm[j] - nm) + __expf(v - nm);
                    cm[j] = nm;
                }
                float rm = fmaxf(fmaxf(v4[0], v4[1]), fmaxf(v4[2], v4[3]));
                float rs = __expf(v4[0] - rm) + __expf(v4[1] - rm)
                         + __expf(v4[2] - rm) + __expf(v4[3] - rm);
                #pragma unroll
                for (int off = 1; off <= 8; off <<= 1) {
                    float om = __shfl_xor(rm, off);
                    float os = __shfl_xor(rs, off);
                    float nm = fmaxf(rm, om);
                    rs = rs * __expf(rm - nm) + os * __expf(om - nm);
                    rm = nm;
                }
                if ((lane & 15) == 0) {
                    redRM[(wid & 1) * 128 + rowLocal] = rm;
                    redRS[(wid & 1) * 128 + rowLocal] = rs;
                }
            }
        }
        #pragma unroll
        for (int j = 0; j < 4; ++j) {
            #pragma unroll
            for (int off = 16; off <= 32; off <<= 1) {
                float om = __shfl_xor(cm[j], off);
                float os = __shfl_xor(cs[j], off);
                float nm = fmaxf(cm[j], om);
                cs[j] = cs[j] * __expf(cm[j] - nm) + os * __expf(om - nm);
                cm[j] = nm;
            }
            if ((lane >> 4) == 0) {
                const int colLocal = wcol + j * 16 + (lane & 15);
                redCM[(wid >> 1) * 128 + colLocal] = cm[j];
                redCS[(wid >> 1) * 128 + colLocal] = cs[j];
            }
        }
        __syncthreads();
        if (tid < 128) {
            float ma = redRM[tid], mb = redRM[128 + tid];
            float sa = redRS[tid], sb = redRS[128 + tid];
            float mm = fmaxf(ma, mb);
            float ss = sa * __expf(ma - mm) + sb * __expf(mb - mm);
            rowM_out[((long)bz * M + m0 + tid) * 4 + blockIdx.x] = mm;
            rowS_out[((long)bz * M + m0 + tid) * 4 + blockIdx.x] = ss;
        } else {
            const int ct = tid - 128;
            float ma = redCM[ct], mb = redCM[128 + ct];
            float sa = redCS[ct], sb = redCS[128 + ct];
            float mm = fmaxf(ma, mb);
            float ss = sa * __expf(ma - mm) + sb * __expf(mb - mm);
            colM_out[((long)bz * NCH + blockIdx.y) * N + n0 + ct] = mm;
            colS_out[((long)bz * NCH + blockIdx.y) * N + n0 + ct] = ss;
        }
    } else {
        #pragma unroll
        for (int i = 0; i < 4; ++i) {
            #pragma unroll
            for (int r = 0; r < 4; ++r) {
                const int row = m0 + wrow + i * 16 + (lane >> 4) * 4 + r;
                #pragma unroll
                for (int j = 0; j < 4; ++j) {
                    const int col = n0 + wcol + j * 16 + (lane & 15);
                    float v = acc[i][j][r];
                    if constexpr (EPI == 0) {
                        C1[cBase + (long)row * ldc + col] = v;
                    } else if constexpr (EPI == 2) {
                        Cb[cBase + (long)row * ldc + col] = f2h(v);
                    } else if constexpr (EPI == 4) {
                        float c = h2f(ctxh[(long)bz * sAux + (long)row * D + col]);
                        float* p = C1 + cBase + (long)row * ldc;
                        p[col] = c;
                        p[D + col] = v;
                        p[2 * D + col] = c * v;
                    } else {  // 5
                        float c = h2f(ctxh[(long)bz * sAux + (long)row * D + col]);
                        C1[cBase + (long)row * ldc + col] = c * v;
                    }
                }
            }
        }
    }
}

// ---------------------------------------------------------------------------
// Fused fp32->f16 convert + row dot with [D,1] weight. One wave per row.
// ---------------------------------------------------------------------------
__global__ __launch_bounds__(256)
void cvtdot(const float* __restrict__ X, const float* __restrict__ wv,
            u16* __restrict__ x16, float* __restrict__ dotv, long rows)
{
    long r = (long)blockIdx.x * 4 + (threadIdx.x >> 6);
    int lane = threadIdx.x & 63;
    if (r >= rows) return;
    const float4* xr = (const float4*)(X + r * D);
    const float4* wr = (const float4*)wv;
    float4 a0 = xr[lane * 2], a1 = xr[lane * 2 + 1];
    float4 b0 = wr[lane * 2], b1 = wr[lane * 2 + 1];
    float s = a0.x * b0.x + a0.y * b0.y + a0.z * b0.z + a0.w * b0.w
            + a1.x * b1.x + a1.y * b1.y + a1.z * b1.z + a1.w * b1.w;
    #pragma unroll
    for (int off = 32; off; off >>= 1) s += __shfl_xor(s, off);
    if (lane == 0) dotv[r] = s;
    ushort4 h0, h1;
    h0.x = f2h(a0.x); h0.y = f2h(a0.y); h0.z = f2h(a0.z); h0.w = f2h(a0.w);
    h1.x = f2h(a1.x); h1.y = f2h(a1.y); h1.z = f2h(a1.z); h1.w = f2h(a1.w);
    *(ushort4*)&x16[r * D + lane * 8] = h0;
    *(ushort4*)&x16[r * D + lane * 8 + 4] = h1;
}

// ---------------------------------------------------------------------------
// fp32 -> (hi, lo) f16 split (dot_weights only)
// ---------------------------------------------------------------------------
__global__ __launch_bounds__(256)
void split_f16(const float* __restrict__ x, u16* __restrict__ hi, u16* __restrict__ lo, long n4)
{
    long i = (long)blockIdx.x * 256 + threadIdx.x;
    if (i >= n4) return;
    float4 v = ((const float4*)x)[i];
    ushort4 h, l;
    h.x = f2h(v.x); l.x = f2h(v.x - h2f(h.x));
    h.y = f2h(v.y); l.y = f2h(v.y - h2f(h.y));
    h.z = f2h(v.z); l.z = f2h(v.z - h2f(h.z));
    h.w = f2h(v.w); l.w = f2h(v.w - h2f(h.w));
    ((ushort4*)hi)[i] = h;
    ((ushort4*)lo)[i] = l;
}

// ---------------------------------------------------------------------------
// G1 split-K reduce: Kt = f16(p0+p1) single (fp32 partials)
// ---------------------------------------------------------------------------
__global__ __launch_bounds__(256)
void g1reduce(const float* __restrict__ p, u16* __restrict__ o, long n4)
{
    long i = (long)blockIdx.x * 256 + threadIdx.x;
    if (i >= n4) return;
    float4 a = ((const float4*)p)[i];
    float4 b = ((const float4*)(p + (long)4096 * 512))[i];
    ushort4 h;
    h.x = f2h(a.x + b.x);
    h.y = f2h(a.y + b.y);
    h.z = f2h(a.z + b.z);
    h.w = f2h(a.w + b.w);
    ((ushort4*)o)[i] = h;
}

// ---------------------------------------------------------------------------
// G4 split-K reduce: Tt = f16(p0+p1), f16 partials
// ---------------------------------------------------------------------------
__global__ __launch_bounds__(256)
void g4reduce(const u16* __restrict__ p, u16* __restrict__ o, long n4)
{
    long i = (long)blockIdx.x * 256 + threadIdx.x;
    if (i >= n4) return;
    ushort4 a = ((const ushort4*)p)[i];
    ushort4 b = ((const ushort4*)(p + (long)Bc * D * Lq))[i];
    ushort4 r;
    r.x = f2h(h2f(a.x) + h2f(b.x));
    r.y = f2h(h2f(a.y) + h2f(b.y));
    r.z = f2h(h2f(a.z) + h2f(b.z));
    r.w = f2h(h2f(a.w) + h2f(b.w));
    ((ushort4*)o)[i] = r;
}

// ---------------------------------------------------------------------------
// Merge partial stats: rows (4 chunks) -> FmR/FrR[B*Lc]; cols (16 chunks)
// -> FmC/FrC[B*Lq]. One thread per output cell.
// ---------------------------------------------------------------------------
__global__ __launch_bounds__(256)
void stat_merge(const float* __restrict__ Rmax, const float* __restrict__ Rsum,
                const float* __restrict__ Pmax, const float* __restrict__ Psum,
                float* __restrict__ FmR, float* __restrict__ FrR,
                float* __restrict__ FmC, float* __restrict__ FrC)
{
    int i = blockIdx.x * 256 + threadIdx.x;
    if (i < Bc * Lc) {
        float4 m4 = ((const float4*)Rmax)[i];
        float4 s4 = ((const float4*)Rsum)[i];
        float m = fmaxf(fmaxf(m4.x, m4.y), fmaxf(m4.z, m4.w));
        float s = s4.x * __expf(m4.x - m) + s4.y * __expf(m4.y - m)
                + s4.z * __expf(m4.z - m) + s4.w * __expf(m4.w - m);
        FmR[i] = m;
        FrR[i] = 1.0f / s;
    } else if (i < Bc * Lc + Bc * Lq) {
        int k = i - Bc * Lc;
        int b = k >> 9, q = k & (Lq - 1);
        const float* pm = Pmax + (long)b * NCH * Lq + q;
        const float* ps = Psum + (long)b * NCH * Lq + q;
        float m = -INFINITY;
        #pragma unroll
        for (int ch = 0; ch < NCH; ++ch) m = fmaxf(m, pm[ch * Lq]);
        float s = 0.f;
        #pragma unroll
        for (int ch = 0; ch < NCH; ++ch) s += ps[ch * Lq] * __expf(pm[ch * Lq] - m);
        FmC[k] = m;
        FrC[k] = 1.0f / s;
    }
}

// ---------------------------------------------------------------------------
// One S read -> BOTH softmax outputs: c2q[row][col] (row-normalized, f16)
// and q2cT[col][row] (col-normalized, transposed via LDS, f16).
// ---------------------------------------------------------------------------
__global__ __launch_bounds__(256)
void softmax_apply(const float* __restrict__ S, u16* __restrict__ c2q,
                   u16* __restrict__ q2cT,
                   const float* __restrict__ FmR, const float* __restrict__ FrR,
                   const float* __restrict__ FmC, const float* __restrict__ FrC)
{
    __shared__ float t[32][33];
    const int b = blockIdx.z;
    const int r0 = blockIdx.y * 32, c0 = blockIdx.x * 32;
    const int tid = threadIdx.x;
    const int rr = tid >> 3, cc = (tid & 7) * 4;
    float4 v = *(const float4*)&S[((long)b * Lc + r0 + rr) * Lq + c0 + cc];
    t[rr][cc] = v.x; t[rr][cc + 1] = v.y; t[rr][cc + 2] = v.z; t[rr][cc + 3] = v.w;
    const float fm = FmR[(long)b * Lc + r0 + rr], fr = FrR[(long)b * Lc + r0 + rr];
    ushort4 o;
    o.x = f2h(__expf(v.x - fm) * fr);
    o.y = f2h(__expf(v.y - fm) * fr);
    o.z = f2h(__expf(v.z - fm) * fr);
    o.w = f2h(__expf(v.w - fm) * fr);
    *(ushort4*)&c2q[((long)b * Lc + r0 + rr) * Lq + c0 + cc] = o;
    __syncthreads();
    const int oc = tid >> 3, orr = (tid & 7) * 4;
    const float fmc = FmC[(long)b * Lq + c0 + oc], frc = FrC[(long)b * Lq + c0 + oc];
    ushort4 q;
    q.x = f2h(__expf(t[orr + 0][oc] - fmc) * frc);
    q.y = f2h(__expf(t[orr + 1][oc] - fmc) * frc);
    q.z = f2h(__expf(t[orr + 2][oc] - fmc) * frc);
    q.w = f2h(__expf(t[orr + 3][oc] - fmc) * frc);
    *(ushort4*)&q2cT[((long)b * Lq + c0 + oc) * Lc + r0 + orr] = q;
}

// ---------------------------------------------------------------------------
// LDS-tiled transpose: f16 [R,C] -> f16 [C,R]
// ---------------------------------------------------------------------------
__global__ __launch_bounds__(256)
void transpose_u16(const u16* __restrict__ in, u16* __restrict__ out,
                   int R, int C, long sIn, long sOut)
{
    __shared__ u16 t[32][34];
    const int b = blockIdx.z;
    in += (long)b * sIn; out += (long)b * sOut;
    const int r0 = blockIdx.y * 32, c0 = blockIdx.x * 32;
    const int tid = threadIdx.x;
    {
        const int rr = tid >> 3, cc = (tid & 7) * 4;
        ushort4 v = *(const ushort4*)&in[(long)(r0 + rr) * C + c0 + cc];
        t[rr][cc] = v.x; t[rr][cc + 1] = v.y; t[rr][cc + 2] = v.z; t[rr][cc + 3] = v.w;
    }
    __syncthreads();
    const int oc = tid >> 3, orr = (tid & 7) * 4;
    ushort4 o;
    o.x = t[orr + 0][oc]; o.y = t[orr + 1][oc]; o.z = t[orr + 2][oc]; o.w = t[orr + 3][oc];
    *(ushort4*)&out[(long)(c0 + oc) * R + r0 + orr] = o;
}

extern "C" void kernel_launch(void* const* d_in, const int* in_sizes, int n_in,
                              void* d_out, int out_size, void* d_ws, size_t ws_size,
                              hipStream_t stream)
{
    const float* context = (const float*)d_in[0];
    const float* query   = (const float*)d_in[1];
    const int*   mask    = (const int*)d_in[2];
    const float* qWt     = (const float*)d_in[3];
    const float* cWt     = (const float*)d_in[4];
    const float* dotW    = (const float*)d_in[5];
    float* out = (float*)d_out;

    char* w = (char*)d_ws;
    size_t off = 0;
    auto alloc = [&](size_t bytes) { void* p = w + off; off += (bytes + 255) & ~(size_t)255; return p; };

    // ctx16: ALIVE for the whole run (G2 A-operand, ctxT source, G3/G5 epilogues)
    u16* ctx16 = (u16*)alloc((size_t)Bc * Lc * D * 2);
    u16* q2cT  = (u16*)alloc((size_t)Bc * Lq * Lc * 2);
    // S region: g1part before G2; ctxT/qT/Tt after the last S read
    float* S = (float*)alloc((size_t)Bc * Lc * Lq * 4);
    float* g1part = S;                                          // [2][4096][512] fp32
    u16* ctxT = (u16*)S;                                        // [B, D, Lc]
    u16* qT   = (u16*)((char*)S + (size_t)Bc * D * Lc * 2);     // [B, D, Lq]
    u16* Tt   = (u16*)((char*)S + (size_t)Bc * D * Lc * 2
                               + (size_t)Bc * D * Lq * 2);      // [B, D, Lq]
    // c2q: own region (no longer aliases ctx16)
    u16* c2q = (u16*)alloc((size_t)Bc * Lc * Lq * 2);
    // q16 then Kt CONTIGUOUS (each 4 MiB, 256-aligned): g4part spans both
    // (q16 dead after transpose_u16/qT; Kt dead after G2 — both before G4)
    u16* q16 = (u16*)alloc((size_t)Bc * Lq * D * 2);
    u16* Kt  = (u16*)alloc((size_t)Bc * Lq * D * 2);
    u16* g4part = q16;   // [2][B][D][Lq] f16 = 8.4 MB
    u16* w_hi  = (u16*)alloc((size_t)D * D * 2);
    u16* w_lo  = (u16*)alloc((size_t)D * D * 2);
    float* cw   = (float*)alloc((size_t)Bc * Lc * 4);
    float* qw   = (float*)alloc((size_t)Bc * Lq * 4);
    float* Rmax = (float*)alloc((size_t)Bc * Lc * 4 * 4);   // [B][Lc][4]
    float* Rsum = (float*)alloc((size_t)Bc * Lc * 4 * 4);
    float* Pmax = (float*)alloc((size_t)Bc * NCH * Lq * 4); // [B][16][Lq]
    float* Psum = (float*)alloc((size_t)Bc * NCH * Lq * 4);
    float* FmR  = (float*)alloc((size_t)Bc * Lc * 4);
    float* FrR  = (float*)alloc((size_t)Bc * Lc * 4);
    float* FmC  = (float*)alloc((size_t)Bc * Lq * 4);
    float* FrC  = (float*)alloc((size_t)Bc * Lq * 4);

    // 1) fused convert + row dots; weight hi/lo split
    cvtdot<<<dim3(Bc * Lc / 4), 256, 0, stream>>>(context, cWt, ctx16, cw, (long)Bc * Lc);
    cvtdot<<<dim3(Bc * Lq / 4), 256, 0, stream>>>(query, qWt, q16, qw, (long)Bc * Lq);
    split_f16<<<dim3(D * D / 4 / 256), 256, 0, stream>>>(dotW, w_hi, w_lo, (long)D * D / 4);

    // 2) G1 splitK=2: partials = q16 @ W^T halves (M=4096 flat, fp32; W hi/lo split)
    gemm_mfma<true, 0, 2, 3><<<dim3(4, 32, 2), 256, 0, stream>>>(
        q16, w_hi, w_lo, g1part, nullptr,
        4096, D, 256, 512, 0, 0, 0, (long)4096 * 512, 512,
        nullptr, nullptr, nullptr, 0, nullptr,
        nullptr, nullptr, nullptr, nullptr);
    g1reduce<<<dim3(2048), 256, 0, stream>>>(g1part, Kt, (long)4096 * 512 / 4);

    // 3) G2: S[b] = ctx_b @ Kt_b^T + biases + mask; fused row/col stat partials
    gemm_mfma<false, 1, 1, 4><<<dim3(4, 16, Bc), 256, 0, stream>>>(
        ctx16, Kt, nullptr, S, nullptr,
        Lc, Lq, D, 512, (long)Lc * D, (long)Lq * D, (long)Lc * Lq, 0, Lq,
        cw, qw, mask, (long)Lc * Lq, nullptr,
        Rmax, Rsum, Pmax, Psum);

    // 4) merge stats (rows 4->1, cols 16->1)
    stat_merge<<<dim3((Bc * Lc + Bc * Lq + 255) / 256), 256, 0, stream>>>(
        Rmax, Rsum, Pmax, Psum, FmR, FrR, FmC, FrC);

    // 5) one S read -> c2q + q2cT
    softmax_apply<<<dim3(Lq / 32, Lc / 32, Bc), 256, 0, stream>>>(
        S, c2q, q2cT, FmR, FrR, FmC, FrC);

    // 6) transposed f16 copies into the now-dead S region (both from f16 sources)
    transpose_u16<<<dim3(D / 32, Lc / 32, Bc), 256, 0, stream>>>(
        ctx16, ctxT, Lc, D, (long)Lc * D, (long)D * Lc);
    transpose_u16<<<dim3(D / 32, Lq / 32, Bc), 256, 0, stream>>>(
        q16, qT, Lq, D, (long)Lq * D, (long)D * Lq);

    // 7) G4 splitK=2: Tt partials = ctxT @ q2cT^T halves (f16 partials in q16+Kt)
    gemm_mfma<false, 2, 2, 4><<<dim3(4, 4, Bc * 2), 256, 0, stream>>>(
        ctxT, q2cT, nullptr, nullptr, g4part,
        D, Lq, 1024, 2048, (long)D * Lc, (long)Lq * Lc, (long)D * Lq, (long)Bc * D * Lq, Lq,
        nullptr, nullptr, nullptr, 0, nullptr,
        nullptr, nullptr, nullptr, nullptr);
    g4reduce<<<dim3(2048), 256, 0, stream>>>(g4part, Tt, (long)Bc * D * Lq / 4);

    // 8) G3: ctq = c2q @ qT^T; epilogue (f16 ctx): out[0:D]=ctx, [D:2D]=ctq, [2D:3D]=ctx*ctq
    gemm_mfma<false, 4, 1, 4><<<dim3(4, 16, Bc), 256, 0, stream>>>(
        c2q, qT, nullptr, out, nullptr,
        Lc, D, Lq, 512, (long)Lc * Lq, (long)D * Lq, (long)Lc * 4 * D, 0, 4 * D,
        nullptr, nullptr, nullptr, (long)Lc * D, ctx16,
        nullptr, nullptr, nullptr, nullptr);

    // 9) G5: qtc = c2q @ Tt^T; epilogue writes out[3D:4D] = ctx*qtc (f16 ctx)
    gemm_mfma<false, 5, 1, 4><<<dim3(4, 16, Bc), 256, 0, stream>>>(
        c2q, Tt, nullptr, out + 3 * D, nullptr,
        Lc, D, Lq, 512, (long)Lc * Lq, (long)D * Lq, (long)Lc * 4 * D, 0, 4 * D,
        nullptr, nullptr, nullptr, (long)Lc * D, ctx16,
        nullptr, nullptr, nullptr, nullptr);
}

// Round 18
// 164.462 us; speedup vs baseline: 1.0393x; 1.0230x over previous
//
#include <hip/hip_runtime.h>
#include <math.h>

#define NEG_BIAS_F (-60000.0f)   // finite in f16; exp(x - max) == 0 for any real max

typedef float    f32x4 __attribute__((ext_vector_type(4)));
typedef _Float16 f16x8 __attribute__((ext_vector_type(8)));
typedef short    s16x8 __attribute__((ext_vector_type(8)));
using u16 = unsigned short;

constexpr int Bc = 8, Lc = 2048, Lq = 512, D = 512;
constexpr int NCH = 16;   // G2 row-chunks (= gridDim.y of G2), 128 rows each

__device__ __forceinline__ u16  f2h(float x) { _Float16 h = (_Float16)x; return __builtin_bit_cast(u16, h); }
__device__ __forceinline__ float h2f(u16 b)  { return (float)__builtin_bit_cast(_Float16, b); }

// async global->LDS, 16B per lane; LDS dest is wave-uniform base (+lane*16 by HW)
__device__ __forceinline__ void gload16(const u16* g, u16* lds) {
    __builtin_amdgcn_global_load_lds(
        (const __attribute__((address_space(1))) void*)g,
        (__attribute__((address_space(3))) void*)lds, 16, 0, 0);
}

__device__ __forceinline__ f32x4 mfma16h(s16x8 a, s16x8 b, f32x4 c) {
    return __builtin_amdgcn_mfma_f32_16x16x32_f16(
        __builtin_bit_cast(f16x8, a), __builtin_bit_cast(f16x8, b), c, 0, 0, 0);
}

// ---------------------------------------------------------------------------
// MFMA NT GEMM: C[m,n] = sum_k A[m,k]*B[n,k], f16. SPLITB: B as hi+lo pair
// (2-MFMA compensated). 128x128 tile, BK=32, 4 waves.
// RING-deep LDS pipeline with COUNTED vmcnt (T4): per iter
//   {vmcnt(min(rem,RING-2)*NLD), s_barrier, compute(t%RING), stage(t+RING-1)}.
// Safety: buf t's loads are always the OLDEST outstanding; the vmcnt proves
// them complete while later tiles stay in flight; each wave's vmcnt precedes
// its barrier => all waves' buf-t writes landed; stage(t+RING-1) overwrites a
// buffer last read in compute(t-1), complete before barrier t for every wave.
// EPI: 0 fp32->C1; 1 S-epilogue (+rowBias+colBias+mask): store f16->Cb with
//        stats computed from the QUANTIZED values (self-consistent softmax;
//        mask bias = -60000, finite in f16 so stat merges never see inf-inf);
//      2 f16->Cb;
//      4 out[0:D]=f16ctx,[D:2D]=v,[2D:3D]=f16ctx*v (ctxh = f16 context);
//      5 C1 = f16ctx*v.
// ---------------------------------------------------------------------------
template<bool SPLITB, int EPI, int SK, int RING>
__global__ __launch_bounds__(256)
void gemm_mfma(const u16* __restrict__ Ah, const u16* __restrict__ Bh,
               const u16* __restrict__ Bl,
               float* __restrict__ C1, u16* __restrict__ Cb,
               int M, int N, int K, int ld,
               long sA, long sB, long sC, long sCk, int ldc,
               const float* __restrict__ aux1, const float* __restrict__ aux2,
               const int* __restrict__ maskp, long sAux,
               const u16* __restrict__ ctxh,
               float* __restrict__ rowM_out, float* __restrict__ rowS_out,
               float* __restrict__ colM_out, float* __restrict__ colS_out)
{
    constexpr int NB = SPLITB ? 3 : 2;
    __shared__ __align__(16) u16 sm[RING * NB * 4096];

    const int bz = blockIdx.z / SK, sk = blockIdx.z % SK;
    const u16* pA  = Ah + (long)bz * sA + (long)sk * K;
    const u16* pBh = Bh + (long)bz * sB + (long)sk * K;
    const u16* pBl = SPLITB ? (Bl + (long)bz * sB + (long)sk * K) : nullptr;

    const int m0 = blockIdx.y * 128, n0 = blockIdx.x * 128;
    const int tid = threadIdx.x, wid = tid >> 6, lane = tid & 63;
    const int wrow = (wid >> 1) * 64, wcol = (wid & 1) * 64;

    const int srow = wid * 16 + (lane >> 2);
    const int skel = (lane & 3) * 8;
    const int sldo = wid * 512;

    f32x4 acc[4][4] = {};

    auto stage = [&](int bsel, int k0) {
        u16* base = sm + bsel * (NB * 4096);
        #pragma unroll
        for (int r = 0; r < 2; ++r) {
            const long goA = (long)(m0 + srow + r * 64) * ld + k0 + skel;
            const long goB = (long)(n0 + srow + r * 64) * ld + k0 + skel;
            const int lo = sldo + r * 2048;
            gload16(pA + goA, base + lo);
            gload16(pBh + goB, base + 4096 + lo);
            if (SPLITB) gload16(pBl + goB, base + 8192 + lo);
        }
    };
    auto compute = [&](int bsel) {
        const u16* As  = sm + bsel * (NB * 4096);
        const u16* BsH = As + 4096;
        const u16* BsL = As + 8192;
        s16x8 a[4], b[4], bl[4];
        #pragma unroll
        for (int f = 0; f < 4; ++f) {
            const int ra = (wrow + f * 16 + (lane & 15)) * 32 + (lane >> 4) * 8;
            const int rb = (wcol + f * 16 + (lane & 15)) * 32 + (lane >> 4) * 8;
            a[f] = *(const s16x8*)&As[ra];
            b[f] = *(const s16x8*)&BsH[rb];
            if (SPLITB) bl[f] = *(const s16x8*)&BsL[rb];
        }
        #pragma unroll
        for (int i = 0; i < 4; ++i)
            #pragma unroll
            for (int j = 0; j < 4; ++j) {
                acc[i][j] = mfma16h(a[i], b[j], acc[i][j]);
                if (SPLITB) acc[i][j] = mfma16h(a[i], bl[j], acc[i][j]);
            }
    };

    const int NT = K / 32;                 // >= RING for all call sites
    #pragma unroll
    for (int p = 0; p < RING - 1; ++p) stage(p, p * 32);
    for (int t = 0; t < NT; ++t) {
        const int rem = NT - 1 - t;
        if constexpr (RING == 4) {
            if (rem >= 2)      asm volatile("s_waitcnt vmcnt(8)" ::: "memory");
            else if (rem == 1) asm volatile("s_waitcnt vmcnt(4)" ::: "memory");
            else               asm volatile("s_waitcnt vmcnt(0)" ::: "memory");
        } else {               // RING == 3
            if (rem >= 1) {
                if constexpr (SPLITB) asm volatile("s_waitcnt vmcnt(6)" ::: "memory");
                else                  asm volatile("s_waitcnt vmcnt(4)" ::: "memory");
            } else {
                asm volatile("s_waitcnt vmcnt(0)" ::: "memory");
            }
        }
        __builtin_amdgcn_s_barrier();
        compute(t % RING);
        if (t + RING - 1 < NT) stage((t + RING - 1) % RING, (t + RING - 1) * 32);
    }
    __syncthreads();                       // quiesce before LDS reuse in epilogue

    // C/D layout (m89-verified): col = lane&15, row = (lane>>4)*4 + reg
    const long cBase = (long)bz * sC + (long)sk * sCk;

    if constexpr (EPI == 1) {
        // ---- fused f16 store + row/col softmax partial stats (on quantized) ----
        float* redRM = (float*)sm;          // [2][128] row halves (by wid&1)
        float* redRS = redRM + 256;
        float* redCM = redRS + 256;         // [2][128] col halves (by wid>>1)
        float* redCS = redCM + 256;

        float cb[4];
        #pragma unroll
        for (int j = 0; j < 4; ++j)
            cb[j] = aux2[(long)bz * N + n0 + wcol + j * 16 + (lane & 15)];
        float cm[4], cs[4];
        #pragma unroll
        for (int j = 0; j < 4; ++j) { cm[j] = -INFINITY; cs[j] = 0.f; }

        #pragma unroll
        for (int i = 0; i < 4; ++i) {
            #pragma unroll
            for (int r = 0; r < 4; ++r) {
                const int rowLocal = wrow + i * 16 + (lane >> 4) * 4 + r;
                const int row = m0 + rowLocal;
                const float rb = aux1[(long)bz * M + row];
                const int* mrow = maskp + (long)bz * sAux + (long)row * N + n0 + wcol + (lane & 15);
                float v4[4];
                #pragma unroll
                for (int j = 0; j < 4; ++j) {
                    float v = acc[i][j][r] + rb + cb[j];
                    v += mrow[j * 16] ? 0.f : NEG_BIAS_F;
                    const u16 hq = f2h(v);
                    const float vq = h2f(hq);   // value the apply pass will read (finite)
                    v4[j] = vq;
                    Cb[cBase + (long)row * ldc + n0 + wcol + j * 16 + (lane & 15)] = hq;
                    float nm = fmaxf(cm[j], vq);
                    cs[j] = cs[j] * __expf(cm[j] - nm) + __expf(vq - nm);
                    cm[j] = nm;
                }
                float rm = fmaxf(fmaxf(v4[0], v4[1]), fmaxf(v4[2], v4[3]));
                float rs = __expf(v4[0] - rm) + __expf(v4[1] - rm)
                         + __expf(v4[2] - rm) + __expf(v4[3] - rm);
                #pragma unroll
                for (int off = 1; off <= 8; off <<= 1) {
                    float om = __shfl_xor(rm, off);
                    float os = __shfl_xor(rs, off);
                    float nm = fmaxf(rm, om);
                    rs = rs * __expf(rm - nm) + os * __expf(om - nm);
                    rm = nm;
                }
                if ((lane & 15) == 0) {
                    redRM[(wid & 1) * 128 + rowLocal] = rm;
                    redRS[(wid & 1) * 128 + rowLocal] = rs;
                }
            }
        }
        #pragma unroll
        for (int j = 0; j < 4; ++j) {
            #pragma unroll
            for (int off = 16; off <= 32; off <<= 1) {
                float om = __shfl_xor(cm[j], off);
                float os = __shfl_xor(cs[j], off);
                float nm = fmaxf(cm[j], om);
                cs[j] = cs[j] * __expf(cm[j] - nm) + os * __expf(om - nm);
                cm[j] = nm;
            }
            if ((lane >> 4) == 0) {
                const int colLocal = wcol + j * 16 + (lane & 15);
                redCM[(wid >> 1) * 128 + colLocal] = cm[j];
                redCS[(wid >> 1) * 128 + colLocal] = cs[j];
            }
        }
        __syncthreads();
        if (tid < 128) {
            float ma = redRM[tid], mb = redRM[128 + tid];
            float sa = redRS[tid], sb = redRS[128 + tid];
            float mm = fmaxf(ma, mb);
            float ss = sa * __expf(ma - mm) + sb * __expf(mb - mm);
            rowM_out[((long)bz * M + m0 + tid) * 4 + blockIdx.x] = mm;
            rowS_out[((long)bz * M + m0 + tid) * 4 + blockIdx.x] = ss;
        } else {
            const int ct = tid - 128;
            float ma = redCM[ct], mb = redCM[128 + ct];
            float sa = redCS[ct], sb = redCS[128 + ct];
            float mm = fmaxf(ma, mb);
            float ss = sa * __expf(ma - mm) + sb * __expf(mb - mm);
            colM_out[((long)bz * NCH + blockIdx.y) * N + n0 + ct] = mm;
            colS_out[((long)bz * NCH + blockIdx.y) * N + n0 + ct] = ss;
        }
    } else {
        #pragma unroll
        for (int i = 0; i < 4; ++i) {
            #pragma unroll
            for (int r = 0; r < 4; ++r) {
                const int row = m0 + wrow + i * 16 + (lane >> 4) * 4 + r;
                #pragma unroll
                for (int j = 0; j < 4; ++j) {
                    const int col = n0 + wcol + j * 16 + (lane & 15);
                    float v = acc[i][j][r];
                    if constexpr (EPI == 0) {
                        C1[cBase + (long)row * ldc + col] = v;
                    } else if constexpr (EPI == 2) {
                        Cb[cBase + (long)row * ldc + col] = f2h(v);
                    } else if constexpr (EPI == 4) {
                        float c = h2f(ctxh[(long)bz * sAux + (long)row * D + col]);
                        float* p = C1 + cBase + (long)row * ldc;
                        p[col] = c;
                        p[D + col] = v;
                        p[2 * D + col] = c * v;
                    } else {  // 5
                        float c = h2f(ctxh[(long)bz * sAux + (long)row * D + col]);
                        C1[cBase + (long)row * ldc + col] = c * v;
                    }
                }
            }
        }
    }
}

// ---------------------------------------------------------------------------
// Fused fp32->f16 convert + row dot with [D,1] weight. One wave per row.
// ---------------------------------------------------------------------------
__global__ __launch_bounds__(256)
void cvtdot(const float* __restrict__ X, const float* __restrict__ wv,
            u16* __restrict__ x16, float* __restrict__ dotv, long rows)
{
    long r = (long)blockIdx.x * 4 + (threadIdx.x >> 6);
    int lane = threadIdx.x & 63;
    if (r >= rows) return;
    const float4* xr = (const float4*)(X + r * D);
    const float4* wr = (const float4*)wv;
    float4 a0 = xr[lane * 2], a1 = xr[lane * 2 + 1];
    float4 b0 = wr[lane * 2], b1 = wr[lane * 2 + 1];
    float s = a0.x * b0.x + a0.y * b0.y + a0.z * b0.z + a0.w * b0.w
            + a1.x * b1.x + a1.y * b1.y + a1.z * b1.z + a1.w * b1.w;
    #pragma unroll
    for (int off = 32; off; off >>= 1) s += __shfl_xor(s, off);
    if (lane == 0) dotv[r] = s;
    ushort4 h0, h1;
    h0.x = f2h(a0.x); h0.y = f2h(a0.y); h0.z = f2h(a0.z); h0.w = f2h(a0.w);
    h1.x = f2h(a1.x); h1.y = f2h(a1.y); h1.z = f2h(a1.z); h1.w = f2h(a1.w);
    *(ushort4*)&x16[r * D + lane * 8] = h0;
    *(ushort4*)&x16[r * D + lane * 8 + 4] = h1;
}

// ---------------------------------------------------------------------------
// fp32 -> (hi, lo) f16 split (dot_weights only)
// ---------------------------------------------------------------------------
__global__ __launch_bounds__(256)
void split_f16(const float* __restrict__ x, u16* __restrict__ hi, u16* __restrict__ lo, long n4)
{
    long i = (long)blockIdx.x * 256 + threadIdx.x;
    if (i >= n4) return;
    float4 v = ((const float4*)x)[i];
    ushort4 h, l;
    h.x = f2h(v.x); l.x = f2h(v.x - h2f(h.x));
    h.y = f2h(v.y); l.y = f2h(v.y - h2f(h.y));
    h.z = f2h(v.z); l.z = f2h(v.z - h2f(h.z));
    h.w = f2h(v.w); l.w = f2h(v.w - h2f(h.w));
    ((ushort4*)hi)[i] = h;
    ((ushort4*)lo)[i] = l;
}

// ---------------------------------------------------------------------------
// G1 split-K reduce: Kt = f16(p0+p1) single (fp32 partials)
// ---------------------------------------------------------------------------
__global__ __launch_bounds__(256)
void g1reduce(const float* __restrict__ p, u16* __restrict__ o, long n4)
{
    long i = (long)blockIdx.x * 256 + threadIdx.x;
    if (i >= n4) return;
    float4 a = ((const float4*)p)[i];
    float4 b = ((const float4*)(p + (long)4096 * 512))[i];
    ushort4 h;
    h.x = f2h(a.x + b.x);
    h.y = f2h(a.y + b.y);
    h.z = f2h(a.z + b.z);
    h.w = f2h(a.w + b.w);
    ((ushort4*)o)[i] = h;
}

// ---------------------------------------------------------------------------
// G4 split-K reduce: Tt = f16(p0+p1), f16 partials
// ---------------------------------------------------------------------------
__global__ __launch_bounds__(256)
void g4reduce(const u16* __restrict__ p, u16* __restrict__ o, long n4)
{
    long i = (long)blockIdx.x * 256 + threadIdx.x;
    if (i >= n4) return;
    ushort4 a = ((const ushort4*)p)[i];
    ushort4 b = ((const ushort4*)(p + (long)Bc * D * Lq))[i];
    ushort4 r;
    r.x = f2h(h2f(a.x) + h2f(b.x));
    r.y = f2h(h2f(a.y) + h2f(b.y));
    r.z = f2h(h2f(a.z) + h2f(b.z));
    r.w = f2h(h2f(a.w) + h2f(b.w));
    ((ushort4*)o)[i] = r;
}

// ---------------------------------------------------------------------------
// Merge partial stats: rows (4 chunks) -> FmR/FrR[B*Lc]; cols (16 chunks)
// -> FmC/FrC[B*Lq]. One thread per output cell.
// ---------------------------------------------------------------------------
__global__ __launch_bounds__(256)
void stat_merge(const float* __restrict__ Rmax, const float* __restrict__ Rsum,
                const float* __restrict__ Pmax, const float* __restrict__ Psum,
                float* __restrict__ FmR, float* __restrict__ FrR,
                float* __restrict__ FmC, float* __restrict__ FrC)
{
    int i = blockIdx.x * 256 + threadIdx.x;
    if (i < Bc * Lc) {
        float4 m4 = ((const float4*)Rmax)[i];
        float4 s4 = ((const float4*)Rsum)[i];
        float m = fmaxf(fmaxf(m4.x, m4.y), fmaxf(m4.z, m4.w));
        float s = s4.x * __expf(m4.x - m) + s4.y * __expf(m4.y - m)
                + s4.z * __expf(m4.z - m) + s4.w * __expf(m4.w - m);
        FmR[i] = m;
        FrR[i] = 1.0f / s;
    } else if (i < Bc * Lc + Bc * Lq) {
        int k = i - Bc * Lc;
        int b = k >> 9, q = k & (Lq - 1);
        const float* pm = Pmax + (long)b * NCH * Lq + q;
        const float* ps = Psum + (long)b * NCH * Lq + q;
        float m = -INFINITY;
        #pragma unroll
        for (int ch = 0; ch < NCH; ++ch) m = fmaxf(m, pm[ch * Lq]);
        float s = 0.f;
        #pragma unroll
        for (int ch = 0; ch < NCH; ++ch) s += ps[ch * Lq] * __expf(pm[ch * Lq] - m);
        FmC[k] = m;
        FrC[k] = 1.0f / s;
    }
}

// ---------------------------------------------------------------------------
// One S (f16) read -> BOTH softmax outputs: c2q[row][col] (row-normalized)
// and q2cT[col][row] (col-normalized, transposed via LDS), both f16.
// ---------------------------------------------------------------------------
__global__ __launch_bounds__(256)
void softmax_apply(const u16* __restrict__ S, u16* __restrict__ c2q,
                   u16* __restrict__ q2cT,
                   const float* __restrict__ FmR, const float* __restrict__ FrR,
                   const float* __restrict__ FmC, const float* __restrict__ FrC)
{
    __shared__ float t[32][33];
    const int b = blockIdx.z;
    const int r0 = blockIdx.y * 32, c0 = blockIdx.x * 32;
    const int tid = threadIdx.x;
    const int rr = tid >> 3, cc = (tid & 7) * 4;
    ushort4 sv = *(const ushort4*)&S[((long)b * Lc + r0 + rr) * Lq + c0 + cc];
    float x0 = h2f(sv.x), x1 = h2f(sv.y), x2 = h2f(sv.z), x3 = h2f(sv.w);
    t[rr][cc] = x0; t[rr][cc + 1] = x1; t[rr][cc + 2] = x2; t[rr][cc + 3] = x3;
    const float fm = FmR[(long)b * Lc + r0 + rr], fr = FrR[(long)b * Lc + r0 + rr];
    ushort4 o;
    o.x = f2h(__expf(x0 - fm) * fr);
    o.y = f2h(__expf(x1 - fm) * fr);
    o.z = f2h(__expf(x2 - fm) * fr);
    o.w = f2h(__expf(x3 - fm) * fr);
    *(ushort4*)&c2q[((long)b * Lc + r0 + rr) * Lq + c0 + cc] = o;
    __syncthreads();
    const int oc = tid >> 3, orr = (tid & 7) * 4;
    const float fmc = FmC[(long)b * Lq + c0 + oc], frc = FrC[(long)b * Lq + c0 + oc];
    ushort4 q;
    q.x = f2h(__expf(t[orr + 0][oc] - fmc) * frc);
    q.y = f2h(__expf(t[orr + 1][oc] - fmc) * frc);
    q.z = f2h(__expf(t[orr + 2][oc] - fmc) * frc);
    q.w = f2h(__expf(t[orr + 3][oc] - fmc) * frc);
    *(ushort4*)&q2cT[((long)b * Lq + c0 + oc) * Lc + r0 + orr] = q;
}

// ---------------------------------------------------------------------------
// Merged LDS-tiled transposes: ctx16 [Lc,D]->ctxT [D,Lc] (blockIdx.y < Lc/32)
// and q16 [Lq,D]->qT [D,Lq] (blockIdx.y >= Lc/32). f16 throughout.
// ---------------------------------------------------------------------------
__global__ __launch_bounds__(256)
void transpose_both(const u16* __restrict__ ctx16, u16* __restrict__ ctxT,
                    const u16* __restrict__ q16, u16* __restrict__ qT)
{
    __shared__ u16 t[32][34];
    const int b = blockIdx.z;
    const u16* in; u16* out; int R; long sIn, sOut;
    int yy = blockIdx.y;
    if (yy < Lc / 32) {
        in = ctx16; out = ctxT; R = Lc; sIn = (long)Lc * D; sOut = (long)D * Lc;
    } else {
        yy -= Lc / 32;
        in = q16; out = qT; R = Lq; sIn = (long)Lq * D; sOut = (long)D * Lq;
    }
    in += (long)b * sIn; out += (long)b * sOut;
    const int r0 = yy * 32, c0 = blockIdx.x * 32;
    const int tid = threadIdx.x;
    {
        const int rr = tid >> 3, cc = (tid & 7) * 4;
        ushort4 v = *(const ushort4*)&in[(long)(r0 + rr) * D + c0 + cc];
        t[rr][cc] = v.x; t[rr][cc + 1] = v.y; t[rr][cc + 2] = v.z; t[rr][cc + 3] = v.w;
    }
    __syncthreads();
    const int oc = tid >> 3, orr = (tid & 7) * 4;
    ushort4 o;
    o.x = t[orr + 0][oc]; o.y = t[orr + 1][oc]; o.z = t[orr + 2][oc]; o.w = t[orr + 3][oc];
    *(ushort4*)&out[(long)(c0 + oc) * R + r0 + orr] = o;
}

extern "C" void kernel_launch(void* const* d_in, const int* in_sizes, int n_in,
                              void* d_out, int out_size, void* d_ws, size_t ws_size,
                              hipStream_t stream)
{
    const float* context = (const float*)d_in[0];
    const float* query   = (const float*)d_in[1];
    const int*   mask    = (const int*)d_in[2];
    const float* qWt     = (const float*)d_in[3];
    const float* cWt     = (const float*)d_in[4];
    const float* dotW    = (const float*)d_in[5];
    float* out = (float*)d_out;

    char* w = (char*)d_ws;
    size_t off = 0;
    auto alloc = [&](size_t bytes) { void* p = w + off; off += (bytes + 255) & ~(size_t)255; return p; };

    // ctx16: ALIVE for the whole run (G2 A-operand, ctxT source, G3/G5 epilogues)
    u16* ctx16 = (u16*)alloc((size_t)Bc * Lc * D * 2);
    u16* q2cT  = (u16*)alloc((size_t)Bc * Lq * Lc * 2);
    // S region (sized 33.5 MB): g1part (fp32, 16.8 MB) before G2; S f16 (16.7 MB)
    // after G2; ctxT/qT/Tt (25.1 MB) after the last S read.
    float* Sreg = (float*)alloc((size_t)Bc * Lc * Lq * 4);
    float* g1part = Sreg;
    u16* S    = (u16*)Sreg;                                     // [B, Lc, Lq] f16
    u16* ctxT = (u16*)Sreg;                                     // [B, D, Lc]
    u16* qT   = (u16*)((char*)Sreg + (size_t)Bc * D * Lc * 2);  // [B, D, Lq]
    u16* Tt   = (u16*)((char*)Sreg + (size_t)Bc * D * Lc * 2
                                   + (size_t)Bc * D * Lq * 2);  // [B, D, Lq]
    // c2q: own region
    u16* c2q = (u16*)alloc((size_t)Bc * Lc * Lq * 2);
    // q16 then Kt CONTIGUOUS: g4part spans both (both dead before G4)
    u16* q16 = (u16*)alloc((size_t)Bc * Lq * D * 2);
    u16* Kt  = (u16*)alloc((size_t)Bc * Lq * D * 2);
    u16* g4part = q16;   // [2][B][D][Lq] f16 = 8.4 MB
    u16* w_hi  = (u16*)alloc((size_t)D * D * 2);
    u16* w_lo  = (u16*)alloc((size_t)D * D * 2);
    float* cw   = (float*)alloc((size_t)Bc * Lc * 4);
    float* qw   = (float*)alloc((size_t)Bc * Lq * 4);
    float* Rmax = (float*)alloc((size_t)Bc * Lc * 4 * 4);   // [B][Lc][4]
    float* Rsum = (float*)alloc((size_t)Bc * Lc * 4 * 4);
    float* Pmax = (float*)alloc((size_t)Bc * NCH * Lq * 4); // [B][16][Lq]
    float* Psum = (float*)alloc((size_t)Bc * NCH * Lq * 4);
    float* FmR  = (float*)alloc((size_t)Bc * Lc * 4);
    float* FrR  = (float*)alloc((size_t)Bc * Lc * 4);
    float* FmC  = (float*)alloc((size_t)Bc * Lq * 4);
    float* FrC  = (float*)alloc((size_t)Bc * Lq * 4);

    // 1) fused convert + row dots; weight hi/lo split
    cvtdot<<<dim3(Bc * Lc / 4), 256, 0, stream>>>(context, cWt, ctx16, cw, (long)Bc * Lc);
    cvtdot<<<dim3(Bc * Lq / 4), 256, 0, stream>>>(query, qWt, q16, qw, (long)Bc * Lq);
    split_f16<<<dim3(D * D / 4 / 256), 256, 0, stream>>>(dotW, w_hi, w_lo, (long)D * D / 4);

    // 2) G1 splitK=2: partials = q16 @ W^T halves (M=4096 flat, fp32; W hi/lo split)
    gemm_mfma<true, 0, 2, 3><<<dim3(4, 32, 2), 256, 0, stream>>>(
        q16, w_hi, w_lo, g1part, nullptr,
        4096, D, 256, 512, 0, 0, 0, (long)4096 * 512, 512,
        nullptr, nullptr, nullptr, 0, nullptr,
        nullptr, nullptr, nullptr, nullptr);
    g1reduce<<<dim3(2048), 256, 0, stream>>>(g1part, Kt, (long)4096 * 512 / 4);

    // 3) G2: S[b] (f16) = ctx_b @ Kt_b^T + biases + mask; stats on quantized values
    gemm_mfma<false, 1, 1, 4><<<dim3(4, 16, Bc), 256, 0, stream>>>(
        ctx16, Kt, nullptr, nullptr, S,
        Lc, Lq, D, 512, (long)Lc * D, (long)Lq * D, (long)Lc * Lq, 0, Lq,
        cw, qw, mask, (long)Lc * Lq, nullptr,
        Rmax, Rsum, Pmax, Psum);

    // 4) merge stats (rows 4->1, cols 16->1)
    stat_merge<<<dim3((Bc * Lc + Bc * Lq + 255) / 256), 256, 0, stream>>>(
        Rmax, Rsum, Pmax, Psum, FmR, FrR, FmC, FrC);

    // 5) one S read -> c2q + q2cT
    softmax_apply<<<dim3(Lq / 32, Lc / 32, Bc), 256, 0, stream>>>(
        S, c2q, q2cT, FmR, FrR, FmC, FrC);

    // 6) merged transposed f16 copies into the now-dead S region
    transpose_both<<<dim3(D / 32, Lc / 32 + Lq / 32, Bc), 256, 0, stream>>>(
        ctx16, ctxT, q16, qT);

    // 7) G4 splitK=2: Tt partials = ctxT @ q2cT^T halves (f16 partials in q16+Kt)
    gemm_mfma<false, 2, 2, 4><<<dim3(4, 4, Bc * 2), 256, 0, stream>>>(
        ctxT, q2cT, nullptr, nullptr, g4part,
        D, Lq, 1024, 2048, (long)D * Lc, (long)Lq * Lc, (long)D * Lq, (long)Bc * D * Lq, Lq,
        nullptr, nullptr, nullptr, 0, nullptr,
        nullptr, nullptr, nullptr, nullptr);
    g4reduce<<<dim3(2048), 256, 0, stream>>>(g4part, Tt, (long)Bc * D * Lq / 4);

    // 8) G3: ctq = c2q @ qT^T; epilogue (f16 ctx): out[0:D]=ctx, [D:2D]=ctq, [2D:3D]=ctx*ctq
    gemm_mfma<false, 4, 1, 4><<<dim3(4, 16, Bc), 256, 0, stream>>>(
        c2q, qT, nullptr, out, nullptr,
        Lc, D, Lq, 512, (long)Lc * Lq, (long)D * Lq, (long)Lc * 4 * D, 0, 4 * D,
        nullptr, nullptr, nullptr, (long)Lc * D, ctx16,
        nullptr, nullptr, nullptr, nullptr);

    // 9) G5: qtc = c2q @ Tt^T; epilogue writes out[3D:4D] = ctx*qtc (f16 ctx)
    gemm_mfma<false, 5, 1, 4><<<dim3(4, 16, Bc), 256, 0, stream>>>(
        c2q, Tt, nullptr, out + 3 * D, nullptr,
        Lc, D, Lq, 512, (long)Lc * Lq, (long)D * Lq, (long)Lc * 4 * D, 0, 4 * D,
        nullptr, nullptr, nullptr, (long)Lc * D, ctx16,
        nullptr, nullptr, nullptr, nullptr);
}